// Round 7
// baseline (154.338 us; speedup 1.0000x reference)
//
#include <hip/hip_runtime.h>
#include <hip/hip_bf16.h>

#define TEMP_INV (1.0f / 0.07f)
#define LOG2E 1.4426950408889634f
#define LN2 0.6931471805599453f
#define CFIX 21.0f

typedef __attribute__((ext_vector_type(16))) float f32x16;
typedef __attribute__((ext_vector_type(8))) short bf16x8;

__device__ __forceinline__ ushort f2bf(float x) {
  union { float f; unsigned u; } v; v.f = x;
  unsigned r = (v.u + 0x7fffu + ((v.u >> 16) & 1u)) >> 16;
  return (ushort)r;
}

__device__ __forceinline__ void gload16(const ushort* g, ushort* l) {
  __builtin_amdgcn_global_load_lds(
      (const __attribute__((address_space(1))) void*)g,
      (__attribute__((address_space(3))) void*)l, 16, 0, 0);
}

// ---------------- Kernel 0: zero the row-sum accumulator ---------------------
__global__ __launch_bounds__(256) void zero_kernel(float* __restrict__ p, int n) {
  const int i = blockIdx.x * 256 + threadIdx.x;
  if (i < n) p[i] = 0.f;
}

// ---------------- Kernel 1: L2-normalize rows, write bf16 feats, cross dot ----
__global__ __launch_bounds__(256) void norm_kernel(
    const float* __restrict__ A, const float* __restrict__ P,
    ushort* __restrict__ F, float* __restrict__ cross, int B, int D) {
  const int row = blockIdx.x;
  const int t = threadIdx.x;
  const float4* a4 = reinterpret_cast<const float4*>(A + (size_t)row * D);
  const float4* p4 = reinterpret_cast<const float4*>(P + (size_t)row * D);
  const int n4 = D >> 2;
  float sa = 0.f, sp = 0.f, sx = 0.f;
  for (int i = t; i < n4; i += 256) {
    float4 av = a4[i], pv = p4[i];
    sa += av.x * av.x + av.y * av.y + av.z * av.z + av.w * av.w;
    sp += pv.x * pv.x + pv.y * pv.y + pv.z * pv.z + pv.w * pv.w;
    sx += av.x * pv.x + av.y * pv.y + av.z * pv.z + av.w * pv.w;
  }
#pragma unroll
  for (int off = 32; off; off >>= 1) {
    sa += __shfl_down(sa, off);
    sp += __shfl_down(sp, off);
    sx += __shfl_down(sx, off);
  }
  __shared__ float red[3][4];
  const int wid = t >> 6, lane = t & 63;
  if (lane == 0) { red[0][wid] = sa; red[1][wid] = sp; red[2][wid] = sx; }
  __syncthreads();
  sa = red[0][0] + red[0][1] + red[0][2] + red[0][3];
  sp = red[1][0] + red[1][1] + red[1][2] + red[1][3];
  sx = red[2][0] + red[2][1] + red[2][2] + red[2][3];
  const float ia = rsqrtf(sa), ip = rsqrtf(sp);
  ushort* fa = F + (size_t)row * D;
  ushort* fp = F + (size_t)(B + row) * D;
  for (int i = t; i < n4; i += 256) {
    float4 av = a4[i], pv = p4[i];
    ushort4 oa, op;
    oa.x = f2bf(av.x * ia); oa.y = f2bf(av.y * ia);
    oa.z = f2bf(av.z * ia); oa.w = f2bf(av.w * ia);
    op.x = f2bf(pv.x * ip); op.y = f2bf(pv.y * ip);
    op.z = f2bf(pv.z * ip); op.w = f2bf(pv.w * ip);
    reinterpret_cast<ushort4*>(fa)[i] = oa;
    reinterpret_cast<ushort4*>(fp)[i] = op;
  }
  if (t == 0) cross[row] = sx * ia * ip;
}

// ---------------- Kernel 2: triangular fused Gram + dual-side exp sums -------
// 128x128 triangle tiles (bx<=by), FULL K=1024, 4 waves x 64x64 wave-tile,
// 32x32x16 MFMA (2x LDS efficiency vs 16x16x32), BK=32 dbuf, 32KB LDS,
// 4 blocks/CU. Dual-side epilogue via atomicAdd; diagonal tiles (bx==by)
// mask self-pairs and skip the j-side (both orderings already in-tile).
// LDS region (128 rows x 32 bf16 = 8KB): same verified layout as R2-R6:
//   (trow,k): lrow=trow>>1; slot=(trow&1)*4+(k>>3); c=slot^(lrow&7);
//   byte=lrow*128+c*16+(k&7)*2.  Staged linear w/ inverse-swizzled source.
__global__ __launch_bounds__(256, 4) void gram_lse_kernel(
    const ushort* __restrict__ F, float* __restrict__ lsum, int NN, int D) {
  __shared__ ushort lds[2][2][4096];  // [buf][A=0/B=1][8KB region]
  const int nrb = NN >> 7;
  const int ntri = nrb * (nrb + 1) / 2;
  int lin = blockIdx.x;
  if ((ntri & 7) == 0) {  // bijective XCD swizzle
    const int per = ntri >> 3;
    lin = (lin & 7) * per + (lin >> 3);
  }
  int by = (int)((sqrtf(8.f * (float)lin + 1.f) - 1.f) * 0.5f);
  while ((by + 1) * (by + 2) / 2 <= lin) ++by;
  while (by * (by + 1) / 2 > lin) --by;
  const int bx = lin - by * (by + 1) / 2;  // bx <= by
  const int r0 = bx * 128;  // i rows (B operand, N side / D cols)
  const int c0 = by * 128;  // j rows (A operand, M side / D rows)
  const bool diag = (bx == by);

  const int t = threadIdx.x;
  const int lane = t & 63, w = t >> 6;      // 4 waves
  const int l31 = lane & 31, l5 = lane >> 5;
  const int wm = w >> 1, wn = w & 1;        // wave covers j rows wm*64, i rows wn*64

  // staging map: wave w, instr g in {0,1} covers LDS chunks (w*2+g)*64 + lane
  const int l3 = lane >> 3, l7 = lane & 7;
  const int cu = l7 ^ l3;
  const int sub = cu >> 2, kc = cu & 3;
  const int trow0 = (w * 2 + 0) * 16 + l3 * 2 + sub;
  const int trow1 = (w * 2 + 1) * 16 + l3 * 2 + sub;
  const ushort* srcA0 = F + (size_t)(c0 + trow0) * D + kc * 8;
  const ushort* srcA1 = F + (size_t)(c0 + trow1) * D + kc * 8;
  const ushort* srcB0 = F + (size_t)(r0 + trow0) * D + kc * 8;
  const ushort* srcB1 = F + (size_t)(r0 + trow1) * D + kc * 8;
  const int dst0 = (w * 2 + 0) * 512;  // ushort offsets (wave-uniform)
  const int dst1 = (w * 2 + 1) * 512;

  // fragment read byte offsets (within 8KB region)
  // frag rows rbase+l31, k16-step s: r=rbase+l31; lrow=r>>1;
  // slot=(r&1)*4+s*2+l5; byte=lrow*128+(slot^(lrow&7))*16
  int offA[2][2], offB[2][2];
#pragma unroll
  for (int m = 0; m < 2; ++m)
#pragma unroll
    for (int s = 0; s < 2; ++s) {
      {
        const int r = wm * 64 + m * 32 + l31;
        const int lrow = r >> 1;
        const int slot = ((r & 1) << 2) + (s << 1) + l5;
        offA[m][s] = lrow * 128 + ((slot ^ (lrow & 7)) << 4);
      }
      {
        const int r = wn * 64 + m * 32 + l31;
        const int lrow = r >> 1;
        const int slot = ((r & 1) << 2) + (s << 1) + l5;
        offB[m][s] = lrow * 128 + ((slot ^ (lrow & 7)) << 4);
      }
    }

  const int nv = D >> 5;  // 32 K-steps

#define STAGE(V, BUF)                                              \
  do {                                                             \
    int v_ = (V); if (v_ > nv - 1) v_ = nv - 1;                    \
    const size_t o_ = (size_t)v_ * 32;                             \
    gload16(srcA0 + o_, &lds[BUF][0][dst0]);                       \
    gload16(srcA1 + o_, &lds[BUF][0][dst1]);                       \
    gload16(srcB0 + o_, &lds[BUF][1][dst0]);                       \
    gload16(srcB1 + o_, &lds[BUF][1][dst1]);                       \
  } while (0)

  f32x16 acc[2][2];
#pragma unroll
  for (int m = 0; m < 2; ++m)
#pragma unroll
    for (int n = 0; n < 2; ++n)
#pragma unroll
      for (int q = 0; q < 16; ++q) acc[m][n][q] = 0.f;

  STAGE(0, 0);  // 4 loads in flight

  for (int v = 0; v < nv; ++v) {
    const int buf = v & 1;
    STAGE(v + 1, buf ^ 1);  // 4 loads; dummy re-stage at v=nv-1 (harmless)
    asm volatile("s_waitcnt vmcnt(4)" ::: "memory");  // stage(v) complete
    asm volatile("" ::: "memory");
    __builtin_amdgcn_s_barrier();
    asm volatile("" ::: "memory");

    const char* RA = (const char*)&lds[buf][0][0];
    const char* RB = (const char*)&lds[buf][1][0];
    bf16x8 am[2][2], bn[2][2];
#pragma unroll
    for (int m = 0; m < 2; ++m)
#pragma unroll
      for (int s = 0; s < 2; ++s) {
        am[m][s] = *(const bf16x8*)(RA + offA[m][s]);
        bn[m][s] = *(const bf16x8*)(RB + offB[m][s]);
      }

    __builtin_amdgcn_s_setprio(1);
#pragma unroll
    for (int s = 0; s < 2; ++s)
#pragma unroll
      for (int m = 0; m < 2; ++m)
#pragma unroll
        for (int n = 0; n < 2; ++n)
          acc[m][n] = __builtin_amdgcn_mfma_f32_32x32x16_bf16(
              am[m][s], bn[n][s], acc[m][n], 0, 0, 0);
    __builtin_amdgcn_s_setprio(0);

    asm volatile("" ::: "memory");
    __builtin_amdgcn_s_barrier();
    asm volatile("" ::: "memory");
  }

  // ---- dual-side epilogue ----
  // acc[m][n][reg]: j_loc = wm*64 + m*32 + (reg&3) + 8*(reg>>2) + 4*l5
  //                 i_loc = wn*64 + n*32 + l31
  const float scl = LOG2E * TEMP_INV;
  float s_i[2] = {0.f, 0.f};
  float s_j[2][16];
#pragma unroll
  for (int m = 0; m < 2; ++m)
#pragma unroll
    for (int q = 0; q < 16; ++q) s_j[m][q] = 0.f;

#pragma unroll
  for (int m = 0; m < 2; ++m) {
#pragma unroll
    for (int n = 0; n < 2; ++n) {
      const int il = wn * 64 + n * 32 + l31;
#pragma unroll
      for (int reg = 0; reg < 16; ++reg) {
        const int jl = wm * 64 + m * 32 + (reg & 3) + ((reg >> 2) << 3) + (l5 << 2);
        float e = exp2f(acc[m][n][reg] * scl - CFIX);
        if (diag && il == jl) e = 0.f;
        s_i[n] += e;
        s_j[m][reg] += e;
      }
    }
  }
  // i-side: reduce over the wave's j coverage (l5 halves), add to rows i
#pragma unroll
  for (int n = 0; n < 2; ++n) {
    float v = s_i[n];
    v += __shfl_xor(v, 32);
    if (l5 == 0) atomicAdd(&lsum[r0 + wn * 64 + n * 32 + l31], v);
  }
  // j-side: reduce over the wave's i coverage (l31 lanes), add to rows j
  if (!diag) {
#pragma unroll
    for (int m = 0; m < 2; ++m)
#pragma unroll
      for (int reg = 0; reg < 16; ++reg) {
        float v = s_j[m][reg];
        v += __shfl_xor(v, 1);
        v += __shfl_xor(v, 2);
        v += __shfl_xor(v, 4);
        v += __shfl_xor(v, 8);
        v += __shfl_xor(v, 16);
        if (l31 == 0)
          atomicAdd(&lsum[c0 + wm * 64 + m * 32 + (reg & 3) +
                          ((reg >> 2) << 3) + (l5 << 2)],
                    v);
      }
  }

  asm volatile("s_waitcnt vmcnt(0)" ::: "memory");
#undef STAGE
}

// ---------------- Kernel 3a: per-row loss -> per-block partial sums ----------
__global__ __launch_bounds__(256) void finalize_part(
    const float* __restrict__ lsum, const float* __restrict__ cross,
    const int* __restrict__ labels, float* __restrict__ bsum,
    float* __restrict__ bcnt, int B) {
  const int NN = 2 * B;
  const int i = blockIdx.x * 256 + threadIdx.x;
  float sum = 0.f, cnt = 0.f;
  if (i < NN) {
    const float lse = LN2 * (CFIX + log2f(lsum[i]));
    const float lab = (float)labels[i % B];
    sum = (lse - cross[i % B] * TEMP_INV) * lab;
    cnt = lab;
  }
#pragma unroll
  for (int off = 32; off; off >>= 1) {
    sum += __shfl_down(sum, off);
    cnt += __shfl_down(cnt, off);
  }
  __shared__ float rs[4], rc[4];
  const int wid = threadIdx.x >> 6, lane = threadIdx.x & 63;
  if (lane == 0) { rs[wid] = sum; rc[wid] = cnt; }
  __syncthreads();
  if (threadIdx.x == 0) {
    bsum[blockIdx.x] = rs[0] + rs[1] + rs[2] + rs[3];
    bcnt[blockIdx.x] = rc[0] + rc[1] + rc[2] + rc[3];
  }
}

// ---------------- Kernel 3b: final reduce ------------------------------------
__global__ __launch_bounds__(64) void finalize_final(
    const float* __restrict__ bsum, const float* __restrict__ bcnt,
    float* __restrict__ out, int nb) {
  const int t = threadIdx.x;
  float s = (t < nb) ? bsum[t] : 0.f;
  float c = (t < nb) ? bcnt[t] : 0.f;
#pragma unroll
  for (int off = 32; off; off >>= 1) {
    s += __shfl_down(s, off);
    c += __shfl_down(c, off);
  }
  if (t == 0) out[0] = (c > 0.f) ? s / c : 0.f;
}

extern "C" void kernel_launch(void* const* d_in, const int* in_sizes, int n_in,
                              void* d_out, int out_size, void* d_ws, size_t ws_size,
                              hipStream_t stream) {
  const float* A = (const float*)d_in[0];
  const float* P = (const float*)d_in[1];
  const int* labels = (const int*)d_in[2];
  float* out = (float*)d_out;
  const int B = in_sizes[2];
  const int D = in_sizes[0] / B;
  const int NN = 2 * B;

  char* ws = (char*)d_ws;
  ushort* F = (ushort*)ws;
  size_t off = (size_t)NN * D * sizeof(ushort);
  off = (off + 255) & ~(size_t)255;
  float* cross = (float*)(ws + off);
  off += (size_t)B * sizeof(float);
  off = (off + 255) & ~(size_t)255;
  float* lsum = (float*)(ws + off);
  off += (size_t)NN * sizeof(float);
  off = (off + 255) & ~(size_t)255;
  float* bsum = (float*)(ws + off);
  off += 64 * sizeof(float);
  float* bcnt = (float*)(ws + off);

  zero_kernel<<<(NN + 255) / 256, 256, 0, stream>>>(lsum, NN);
  norm_kernel<<<B, 256, 0, stream>>>(A, P, F, cross, B, D);
  const int nrb = NN >> 7;               // 64 row-panels of 128
  const int ntri = nrb * (nrb + 1) / 2;  // 2080 triangle tiles, full K each
  gram_lse_kernel<<<ntri, 256, 0, stream>>>(F, lsum, NN, D);
  const int nb = (NN + 255) / 256;  // 32
  finalize_part<<<nb, 256, 0, stream>>>(lsum, cross, labels, bsum, bcnt, B);
  finalize_final<<<1, 64, 0, stream>>>(bsum, bcnt, out, nb);
}